// Round 1
// baseline (73.802 us; speedup 1.0000x reference)
//
#include <hip/hip_runtime.h>

struct cplx { float re, im; };

__device__ __forceinline__ cplx cmul(cplx a, cplx b) {
    return { a.re * b.re - a.im * b.im, a.re * b.im + a.im * b.re };
}
__device__ __forceinline__ cplx cadd(cplx a, cplx b) { return { a.re + b.re, a.im + b.im }; }

// Apply a 2x2 complex gate to the wire whose index-bit mask is MASK (wire w -> MASK = 8 >> w).
template<int MASK>
__device__ __forceinline__ void apply1(cplx st[16], cplx m00, cplx m01, cplx m10, cplx m11) {
#pragma unroll
    for (int i = 0; i < 16; ++i) {
        if (i & MASK) continue;
        cplx a0 = st[i], a1 = st[i | MASK];
        st[i]        = cadd(cmul(m00, a0), cmul(m01, a1));
        st[i | MASK] = cadd(cmul(m10, a0), cmul(m11, a1));
    }
}

__device__ __forceinline__ void cswap(cplx& a, cplx& b) { cplx t = a; a = b; b = t; }

__global__ __launch_bounds__(256) void qfilter_kernel(const float4* __restrict__ x,
                                                      const float* __restrict__ params,
                                                      float4* __restrict__ out, int B) {
    int b = blockIdx.x * blockDim.x + threadIdx.x;
    if (b >= B) return;

    float4 xv = x[b];
    float cx[4], sx[4];
    sincosf(0.5f * xv.x, &sx[0], &cx[0]);
    sincosf(0.5f * xv.y, &sx[1], &cx[1]);
    sincosf(0.5f * xv.z, &sx[2], &cx[2]);
    sincosf(0.5f * xv.w, &sx[3], &cx[3]);

    // Angle-embedding RY on each wire starting from |0000>: product state, real.
    // wire 0 = MSB of the 4-bit index.
    cplx st[16];
#pragma unroll
    for (int i = 0; i < 16; ++i) {
        float a = (((i >> 3) & 1) ? sx[0] : cx[0]) *
                  (((i >> 2) & 1) ? sx[1] : cx[1]) *
                  (((i >> 1) & 1) ? sx[2] : cx[2]) *
                  (((i     ) & 1) ? sx[3] : cx[3]);
        st[i] = { a, 0.0f };
    }

    float p0 = params[0], p1 = params[1], p2 = params[2], p3 = params[3], p4 = params[4];
    float c, s;

    // RX(p0) on wire 0: [[c, -is], [-is, c]]
    sincosf(0.5f * p0, &s, &c);
    apply1<8>(st, {c, 0.f}, {0.f, -s}, {0.f, -s}, {c, 0.f});

    // RY(p1) on wire 1: [[c, -s], [s, c]]
    sincosf(0.5f * p1, &s, &c);
    apply1<4>(st, {c, 0.f}, {-s, 0.f}, {s, 0.f}, {c, 0.f});

    // RZ(p2) on wire 2: diag(e^{-it/2}, e^{+it/2})  (zero off-diagonals fold away)
    sincosf(0.5f * p2, &s, &c);
    apply1<2>(st, {c, -s}, {0.f, 0.f}, {0.f, 0.f}, {c, s});

    // RX(p3) on wire 3
    sincosf(0.5f * p3, &s, &c);
    apply1<1>(st, {c, 0.f}, {0.f, -s}, {0.f, -s}, {c, 0.f});

    // CNOT(control wire0, target wire1): for bit0(MSB)=1, flip bit1 -> swap |10xx> <-> |11xx>
    cswap(st[8], st[12]); cswap(st[9], st[13]); cswap(st[10], st[14]); cswap(st[11], st[15]);

    // CNOT(control wire2, target wire3): for bit2=1, flip bit3 -> swap |xx10> <-> |xx11>
    cswap(st[2], st[3]); cswap(st[6], st[7]); cswap(st[10], st[11]); cswap(st[14], st[15]);

    // RY(p4) on wire 2
    sincosf(0.5f * p4, &s, &c);
    apply1<2>(st, {c, 0.f}, {-s, 0.f}, {s, 0.f}, {c, 0.f});

    // RZ(p5) on wire 0: pure per-basis phase -> |amp|^2 unchanged. Exactly skippable.

    float e0 = 0.f, e1 = 0.f, e2 = 0.f, e3 = 0.f;
#pragma unroll
    for (int i = 0; i < 16; ++i) {
        float pr = st[i].re * st[i].re + st[i].im * st[i].im;
        e0 += ((i >> 3) & 1) ? -pr : pr;
        e1 += ((i >> 2) & 1) ? -pr : pr;
        e2 += ((i >> 1) & 1) ? -pr : pr;
        e3 += ((i     ) & 1) ? -pr : pr;
    }
    out[b] = make_float4(e0, e1, e2, e3);
}

extern "C" void kernel_launch(void* const* d_in, const int* in_sizes, int n_in,
                              void* d_out, int out_size, void* d_ws, size_t ws_size,
                              hipStream_t stream) {
    const int B = in_sizes[0] / 4;               // x is [B,4] float32
    const float4* x      = (const float4*)d_in[0];
    const float*  params = (const float*)d_in[1];
    float4*       out    = (float4*)d_out;       // [B,4] float32

    const int threads = 256;
    const int blocks = (B + threads - 1) / threads;
    qfilter_kernel<<<blocks, threads, 0, stream>>>(x, params, out, B);
}

// Round 2
// 60.706 us; speedup vs baseline: 1.2157x; 1.2157x over previous
//
#include <hip/hip_runtime.h>

// QuantumFilter: 4-qubit circuit, B=524288.
// The circuit factorizes: qubit pairs {0,1} and {2,3} never interact
// (only 2q gates are CNOT(0,1) and CNOT(2,3)); final RZ(p5) is diagonal
// (no effect on Z expectations). Closed form (derived analytically,
// spot-checked against the reference semantics):
//   Z0 = cos(p0)*cos(x0)
//   Z1 = cos(p0)*cos(x0)*cos(x1 + p1)          // RY angles compose additively
//   Z2 = cos(p4)*cos(x2) - sin(p4)*cos(p2)*sin(x2)*sin(x3)
//   Z3 = cos(p3)*cos(x3)*cos(x2)
// Exact math; only trig rounding (~1e-5 with hardware v_cos_f32) vs 2e-2 threshold.

__global__ __launch_bounds__(256) void qfilter_kernel(const float4* __restrict__ x,
                                                      const float* __restrict__ params,
                                                      float4* __restrict__ out, int B) {
    int b = blockIdx.x * blockDim.x + threadIdx.x;
    if (b >= B) return;

    float4 xv = x[b];

    // Wave-uniform param-derived scalars (cheap: 5 hardware trig ops).
    float p1  = params[1];
    float cp0 = __cosf(params[0]);
    float cp2 = __cosf(params[2]);
    float cp3 = __cosf(params[3]);
    float sp4, cp4;
    __sincosf(params[4], &sp4, &cp4);

    float c0 = __cosf(xv.x);
    float c1 = __cosf(xv.y + p1);
    float s2, c2; __sincosf(xv.z, &s2, &c2);
    float s3, c3; __sincosf(xv.w, &s3, &c3);

    float o0 = cp0 * c0;
    float o1 = o0 * c1;
    float o2 = cp4 * c2 - sp4 * cp2 * s2 * s3;
    float o3 = cp3 * c3 * c2;

    out[b] = make_float4(o0, o1, o2, o3);
}

extern "C" void kernel_launch(void* const* d_in, const int* in_sizes, int n_in,
                              void* d_out, int out_size, void* d_ws, size_t ws_size,
                              hipStream_t stream) {
    const int B = in_sizes[0] / 4;               // x is [B,4] float32
    const float4* x      = (const float4*)d_in[0];
    const float*  params = (const float*)d_in[1];
    float4*       out    = (float4*)d_out;       // [B,4] float32

    const int threads = 256;
    const int blocks = (B + threads - 1) / threads;
    qfilter_kernel<<<blocks, threads, 0, stream>>>(x, params, out, B);
}